// Round 8
// baseline (259.308 us; speedup 1.0000x reference)
//
#include <hip/hip_runtime.h>

#define T_STEPS 512
#define HSTR 80        // _Float16 per h batch-row (160 B)
#define XSTRIDE 520    // _Float16 per x-row
#define OSTRIDE 513    // floats per out-row
#define NB 4           // batches per block; 512 blocks = 2 blocks/CU

typedef _Float16 half8v __attribute__((ext_vector_type(8)));
typedef _Float16 half4v __attribute__((ext_vector_type(4)));
typedef float f32x4 __attribute__((ext_vector_type(4)));

#define K1 1.442695041f    // log2(e)
#define K2 2.885390082f    // 2*log2(e)
#define CZCL 43.28085123f  // 15*K2, clamp in cz = cs*K2 domain

__device__ __forceinline__ float ex2(float x) {
#if __has_builtin(__builtin_amdgcn_exp2f)
    return __builtin_amdgcn_exp2f(x);
#else
    return exp2f(x);
#endif
}
__device__ __forceinline__ float rcp_fast(float x) {
#if __has_builtin(__builtin_amdgcn_rcpf)
    return __builtin_amdgcn_rcpf(x);
#else
    return 1.0f / x;
#endif
}

// partial fc-dot over this lane's A-frag slice (f16), reduced over the 4 k-quads
__device__ __forceinline__ float out_dot(half8v a0, half8v a1,
                                         const float* wfc0, const float* wfc1) {
    float s = 0.f;
#pragma unroll
    for (int j = 0; j < 8; ++j) s = fmaf((float)a0[j], wfc0[j], s);
#pragma unroll
    for (int j = 0; j < 8; ++j) s = fmaf((float)a1[j], wfc1[j], s);
    s += __shfl_xor(s, 16);
    s += __shfl_xor(s, 32);
    return s;   // full 64-dot for batch (c>>2), on all lanes
}

// R18 = R15 champion + ONE change (attribution round, R17 regressed with two):
//   MFMA pair UN-chained: acc0=MFMA(a0,B0,0) and acc1=MFMA(a1,B1,0) are
//   independent; elem-0 partials summed in VALU with xb folded into acc0
//   (which finishes first) -> removes one MFMA dependency latency from the
//   recurrence. Act block is BIT-IDENTICAL to R15 (single rcp in h-tail;
//   R17's extra-rcp tail is reverted).
// Topology: NB=4, 4 waves, 2 blocks/CU, A rows m -> h[m>>2], one act chain
// per lane (batch q, unit 16w+c), 1 barrier/step, fc-dot in the dt==0
// ds_read latency shadow, cz = cs*K2 domain.
__global__ __launch_bounds__(256, 2) void lstm_kernel(
    const float* __restrict__ x, const float* __restrict__ w_ih,
    const float* __restrict__ w_hh, const float* __restrict__ b_ih,
    const float* __restrict__ b_hh, const float* __restrict__ w_fc,
    const float* __restrict__ b_fc, float* __restrict__ out)
{
    __shared__ __align__(16) _Float16 hbuf[2][NB * HSTR];   // 1.3 KB
    __shared__ __align__(16) _Float16 xls[NB * XSTRIDE];    // 4.2 KB
    __shared__ __align__(16) float ols[NB * OSTRIDE];       // 8.2 KB

    const int tid  = threadIdx.x;
    const int w    = tid >> 6;        // wave 0..3
    const int lane = tid & 63;
    const int q    = lane >> 4;       // quad (A k-group / D row-group)
    const int c    = lane & 15;       // unit-in-tile / A-row
    const int b0   = blockIdx.x * NB;

    // ---- stage x: global -> LDS (f16), coalesced float4 reads ----
    for (int i = tid; i < NB * 128; i += 256) {      // 4 rows x 128 float4
        int b  = i >> 7;
        int t4 = i & 127;
        float4 v = *(const float4*)(x + (size_t)(b0 + b) * T_STEPS + t4 * 4);
        half4v hv;
        hv[0] = (_Float16)v.x; hv[1] = (_Float16)v.y;
        hv[2] = (_Float16)v.z; hv[3] = (_Float16)v.w;
        *(half4v*)(&xls[b * XSTRIDE + t4 * 4]) = hv;
    }
    // zero both h buffers (h_{-1} = 0)
    for (int i = tid; i < 2 * NB * HSTR / 2; i += 256) ((int*)hbuf)[i] = 0;

    // ---- B fragments (prescaled weights): tile n = gate class ----
    // lane (q,c) holds B[k=32kk+8q+jj][col c] = sK[n]*w_hh[g][k], g = 64n+16w+c
    const float sK[4] = { -K1, -K1, K2, -K1 };   // i,f sig; g tanh; o sig
    half8v bfrag[4][2];
    float biasS[4], wihS[4];
#pragma unroll
    for (int n = 0; n < 4; ++n) {
        int g = 64 * n + 16 * w + c;
        biasS[n] = (b_ih[g] + b_hh[g]) * sK[n];
        wihS[n]  = w_ih[g] * sK[n];
#pragma unroll
        for (int kk = 0; kk < 2; ++kk) {
            const float* wp = w_hh + g * 64 + 32 * kk + 8 * q;
            float4 lo  = *(const float4*)(wp);
            float4 hi4 = *(const float4*)(wp + 4);
            half8v f;
            f[0] = (_Float16)(lo.x  * sK[n]); f[1] = (_Float16)(lo.y  * sK[n]);
            f[2] = (_Float16)(lo.z  * sK[n]); f[3] = (_Float16)(lo.w  * sK[n]);
            f[4] = (_Float16)(hi4.x * sK[n]); f[5] = (_Float16)(hi4.y * sK[n]);
            f[6] = (_Float16)(hi4.z * sK[n]); f[7] = (_Float16)(hi4.w * sK[n]);
            bfrag[n][kk] = f;
        }
    }

    // fc weights aligned to this lane's A-frag k-slice
    float wfc0[8], wfc1[8];
#pragma unroll
    for (int j = 0; j < 8; ++j) { wfc0[j] = w_fc[8 * q + j]; wfc1[j] = w_fc[32 + 8 * q + j]; }
    const float bfc = b_fc[0];

    float cz = 0.f;               // cell state * K2 (batch q, unit 16w+c)
    const f32x4 zeroq = {0.f, 0.f, 0.f, 0.f};

    __syncthreads();

    half8v sa0 = {}, sa1 = {};  // saved A-frags for rotated fc-dot

    for (int tq = 0; tq < 128; ++tq) {
        // x for this lane's OWN batch (q), 4 steps (broadcast read)
        half4v xh = *(const half4v*)(&xls[q * XSTRIDE + tq * 4]);

#pragma unroll
        for (int dt = 0; dt < 4; ++dt) {
            const int t  = tq * 4 + dt;
            const int rb = t & 1;

            // A-frags: A[m][k] = h[m>>2][k]; lane row m=c -> LDS row c>>2
            const _Float16* hp = hbuf[rb] + (c >> 2) * HSTR + 8 * q;
            half8v a0 = *(const half8v*)(hp);        // k = 8q+j
            half8v a1 = *(const half8v*)(hp + 32);   // k = 32+8q+j

            if (dt == 0) {
                // pending fc-dot from previous tq, issued in the ds_read
                // latency shadow (independent of a0/a1). Saved frag was the
                // A of step stp = 4(tq-1)+w = h(stp-1) -> column stp-1.
                int stp = 4 * tq - 4 + w;
                if (tq > 0 && stp > 0) {
                    float s = out_dot(sa0, sa1, wfc0, wfc1);
                    if (lane < 16 && (lane & 3) == 0)
                        ols[(lane >> 2) * OSTRIDE + (stp - 1)] = s + bfc;
                }
            }

            if (dt == w) { sa0 = a0; sa1 = a1; }     // rotate fc-dot ownership

            // scalar x*wih+bias for the owned batch (off critical path)
            const float xv = (float)xh[dt];
            float xb[4];
#pragma unroll
            for (int n = 0; n < 4; ++n) xb[n] = fmaf(xv, wihS[n], biasS[n]);

            // gates: 4 class tiles, K=64 via two INDEPENDENT MFMAs (no
            // C-chain); elem-0 partials summed in VALU, xb folded into the
            // earlier-finishing acc0 while acc1 completes
            f32x4 acc0[4], acc1[4];
#pragma unroll
            for (int n = 0; n < 4; ++n)
                acc0[n] = __builtin_amdgcn_mfma_f32_16x16x32_f16(a0, bfrag[n][0], zeroq, 0, 0, 0);
#pragma unroll
            for (int n = 0; n < 4; ++n)
                acc1[n] = __builtin_amdgcn_mfma_f32_16x16x32_f16(a1, bfrag[n][1], zeroq, 0, 0, 0);

            // rows 4q..4q+3 are all batch q -> elem 0, no select needed
            float v0 = (acc0[0][0] + xb[0]) + acc1[0][0];
            float v1 = (acc0[1][0] + xb[1]) + acc1[1][0];
            float v2 = (acc0[2][0] + xb[2]) + acc1[2][0];
            float v3 = (acc0[3][0] + xb[3]) + acc1[3][0];

            // fused activations, cz = cs*K2 domain (BIT-IDENTICAL to R15)
            {
                float A   = ex2(v0);                    // e^{-i}
                float Bt  = ex2(v2);                    // e^{2g}
                float R   = rcp_fast((1.0f + A) * (1.0f + Bt));
                float pg  = fmaf(Bt, K2, -K2);          // (Bt-1)*K2
                float igk = pg * R;                     // i*g * K2
                float rf  = rcp_fast(1.0f + ex2(v1));   // sig(f)
                cz = fmaf(cz, rf, igk);
                float cc = fminf(fmaxf(cz, -CZCL), CZCL);
                float Ao = ex2(v3);                     // e^{-o}
                float C  = ex2(cc);                     // e^{2c}
                float h  = (C - 1.0f) * rcp_fast((1.0f + Ao) * (1.0f + C));
                hbuf[rb ^ 1][q * HSTR + 16 * w + c] = (_Float16)h;
            }
            __syncthreads();
        }
    }

    // epilogue pending fc-dot: saved frag from tq=127 -> st = 508+w,
    // column 507+w (covers 507..510)
    {
        float s = out_dot(sa0, sa1, wfc0, wfc1);
        if (lane < 16 && (lane & 3) == 0)
            ols[(lane >> 2) * OSTRIDE + (507 + w)] = s + bfc;
    }

    // final output column: h_511 lives in hbuf[0]
    if (w == 3) {
        const _Float16* hp = hbuf[0] + (c >> 2) * HSTR + 8 * q;
        half8v a0 = *(const half8v*)(hp);
        half8v a1 = *(const half8v*)(hp + 32);
        float s = out_dot(a0, a1, wfc0, wfc1);
        if (lane < 16 && (lane & 3) == 0)
            ols[(lane >> 2) * OSTRIDE + (T_STEPS - 1)] = s + bfc;
    }
    __syncthreads();

    // bulk store: LDS out -> global, coalesced
    for (int i = tid; i < NB * T_STEPS; i += 256) {
        int b = i >> 9;
        int t = i & (T_STEPS - 1);
        out[(size_t)(b0 + b) * T_STEPS + t] = ols[b * OSTRIDE + t];
    }
}

extern "C" void kernel_launch(void* const* d_in, const int* in_sizes, int n_in,
                              void* d_out, int out_size, void* d_ws, size_t ws_size,
                              hipStream_t stream) {
    const float* x    = (const float*)d_in[0];
    const float* w_ih = (const float*)d_in[1];
    const float* w_hh = (const float*)d_in[2];
    const float* b_ih = (const float*)d_in[3];
    const float* b_hh = (const float*)d_in[4];
    const float* w_fc = (const float*)d_in[5];
    const float* b_fc = (const float*)d_in[6];
    float* out = (float*)d_out;
    hipLaunchKernelGGL(lstm_kernel, dim3(2048 / NB), dim3(256), 0, stream,
                       x, w_ih, w_hh, b_ih, b_hh, w_fc, b_fc, out);
}

// Round 9
// 250.249 us; speedup vs baseline: 1.0362x; 1.0362x over previous
//
#include <hip/hip_runtime.h>

#define T_STEPS 512
#define HSTR 80        // _Float16 per h batch-row (160 B)
#define XSTRIDE 520    // _Float16 per x-row
#define OSTRIDE 513    // floats per out-row
#define NB 4           // batches per block; 512 blocks = 2 blocks/CU

typedef _Float16 half8v __attribute__((ext_vector_type(8)));
typedef _Float16 half4v __attribute__((ext_vector_type(4)));
typedef float f32x4 __attribute__((ext_vector_type(4)));

#define K1 1.442695041f    // log2(e)
#define K2 2.885390082f    // 2*log2(e)
#define CZMX 88.0f         // one-sided clamp: ex2(+88) finite; neg side self-correct

__device__ __forceinline__ float ex2(float x) {
#if __has_builtin(__builtin_amdgcn_exp2f)
    return __builtin_amdgcn_exp2f(x);
#else
    return exp2f(x);
#endif
}
__device__ __forceinline__ float rcp_fast(float x) {
#if __has_builtin(__builtin_amdgcn_rcpf)
    return __builtin_amdgcn_rcpf(x);
#else
    return 1.0f / x;
#endif
}

// partial fc-dot over this lane's A-frag slice (f16), reduced over the 4 k-quads
__device__ __forceinline__ float out_dot(half8v a0, half8v a1,
                                         const float* wfc0, const float* wfc1) {
    float s = 0.f;
#pragma unroll
    for (int j = 0; j < 8; ++j) s = fmaf((float)a0[j], wfc0[j], s);
#pragma unroll
    for (int j = 0; j < 8; ++j) s = fmaf((float)a1[j], wfc1[j], s);
    s += __shfl_xor(s, 16);
    s += __shfl_xor(s, 32);
    return s;   // full 64-dot for batch (c>>2), on all lanes
}

// R19 = R15 champion (CHAINED MFMA pair kept -- R17/R18 proved un-chaining
// costs ~+12us) + act-path shortening trio:
//  (1) MFMA issue order 2,1,0,3: cz-critical gates (g=idx2, f=idx1) finish
//      first so their ex2/rcp issue while acc[0]/acc[3] complete.
//  (2) h-tail: h = fmaf(-2Ro, rcp(1+C), Ro); Ro = rcp(1+ex2(v3)) and -2Ro
//      computed OFF the cz path -> post-C depth = add->rcp->fma.
//  (3) one-sided clamp fminf(cz, 88): ex2 underflow handles the neg side
//      exactly (h -> -Ro = o*(-1)), drops one VALU from the path.
// Topology: NB=4, 4 waves, 2 blocks/CU, A rows m -> h[m>>2], one act chain
// per lane (batch q, unit 16w+c), 1 barrier/step, fc-dot in the dt==0
// ds_read latency shadow, cz = cs*K2 domain.
__global__ __launch_bounds__(256, 2) void lstm_kernel(
    const float* __restrict__ x, const float* __restrict__ w_ih,
    const float* __restrict__ w_hh, const float* __restrict__ b_ih,
    const float* __restrict__ b_hh, const float* __restrict__ w_fc,
    const float* __restrict__ b_fc, float* __restrict__ out)
{
    __shared__ __align__(16) _Float16 hbuf[2][NB * HSTR];   // 1.3 KB
    __shared__ __align__(16) _Float16 xls[NB * XSTRIDE];    // 4.2 KB
    __shared__ __align__(16) float ols[NB * OSTRIDE];       // 8.2 KB

    const int tid  = threadIdx.x;
    const int w    = tid >> 6;        // wave 0..3
    const int lane = tid & 63;
    const int q    = lane >> 4;       // quad (A k-group / D row-group)
    const int c    = lane & 15;       // unit-in-tile / A-row
    const int b0   = blockIdx.x * NB;

    // ---- stage x: global -> LDS (f16), coalesced float4 reads ----
    for (int i = tid; i < NB * 128; i += 256) {      // 4 rows x 128 float4
        int b  = i >> 7;
        int t4 = i & 127;
        float4 v = *(const float4*)(x + (size_t)(b0 + b) * T_STEPS + t4 * 4);
        half4v hv;
        hv[0] = (_Float16)v.x; hv[1] = (_Float16)v.y;
        hv[2] = (_Float16)v.z; hv[3] = (_Float16)v.w;
        *(half4v*)(&xls[b * XSTRIDE + t4 * 4]) = hv;
    }
    // zero both h buffers (h_{-1} = 0)
    for (int i = tid; i < 2 * NB * HSTR / 2; i += 256) ((int*)hbuf)[i] = 0;

    // ---- B fragments (prescaled weights): tile n = gate class ----
    // lane (q,c) holds B[k=32kk+8q+jj][col c] = sK[n]*w_hh[g][k], g = 64n+16w+c
    const float sK[4] = { -K1, -K1, K2, -K1 };   // i,f sig; g tanh; o sig
    half8v bfrag[4][2];
    float biasS[4], wihS[4];
#pragma unroll
    for (int n = 0; n < 4; ++n) {
        int g = 64 * n + 16 * w + c;
        biasS[n] = (b_ih[g] + b_hh[g]) * sK[n];
        wihS[n]  = w_ih[g] * sK[n];
#pragma unroll
        for (int kk = 0; kk < 2; ++kk) {
            const float* wp = w_hh + g * 64 + 32 * kk + 8 * q;
            float4 lo  = *(const float4*)(wp);
            float4 hi4 = *(const float4*)(wp + 4);
            half8v f;
            f[0] = (_Float16)(lo.x  * sK[n]); f[1] = (_Float16)(lo.y  * sK[n]);
            f[2] = (_Float16)(lo.z  * sK[n]); f[3] = (_Float16)(lo.w  * sK[n]);
            f[4] = (_Float16)(hi4.x * sK[n]); f[5] = (_Float16)(hi4.y * sK[n]);
            f[6] = (_Float16)(hi4.z * sK[n]); f[7] = (_Float16)(hi4.w * sK[n]);
            bfrag[n][kk] = f;
        }
    }

    // fc weights aligned to this lane's A-frag k-slice
    float wfc0[8], wfc1[8];
#pragma unroll
    for (int j = 0; j < 8; ++j) { wfc0[j] = w_fc[8 * q + j]; wfc1[j] = w_fc[32 + 8 * q + j]; }
    const float bfc = b_fc[0];

    float cz = 0.f;               // cell state * K2 (batch q, unit 16w+c)
    const f32x4 zeroq = {0.f, 0.f, 0.f, 0.f};

    __syncthreads();

    half8v sa0 = {}, sa1 = {};  // saved A-frags for rotated fc-dot

    for (int tq = 0; tq < 128; ++tq) {
        // x for this lane's OWN batch (q), 4 steps (broadcast read)
        half4v xh = *(const half4v*)(&xls[q * XSTRIDE + tq * 4]);

#pragma unroll
        for (int dt = 0; dt < 4; ++dt) {
            const int t  = tq * 4 + dt;
            const int rb = t & 1;

            // A-frags: A[m][k] = h[m>>2][k]; lane row m=c -> LDS row c>>2
            const _Float16* hp = hbuf[rb] + (c >> 2) * HSTR + 8 * q;
            half8v a0 = *(const half8v*)(hp);        // k = 8q+j
            half8v a1 = *(const half8v*)(hp + 32);   // k = 32+8q+j

            if (dt == 0) {
                // pending fc-dot from previous tq, issued in the ds_read
                // latency shadow (independent of a0/a1). Saved frag was the
                // A of step stp = 4(tq-1)+w = h(stp-1) -> column stp-1.
                int stp = 4 * tq - 4 + w;
                if (tq > 0 && stp > 0) {
                    float s = out_dot(sa0, sa1, wfc0, wfc1);
                    if (lane < 16 && (lane & 3) == 0)
                        ols[(lane >> 2) * OSTRIDE + (stp - 1)] = s + bfc;
                }
            }

            if (dt == w) { sa0 = a0; sa1 = a1; }     // rotate fc-dot ownership

            // scalar x*wih+bias for the owned batch (off critical path)
            const float xv = (float)xh[dt];
            float xb[4];
#pragma unroll
            for (int n = 0; n < 4; ++n) xb[n] = fmaf(xv, wihS[n], biasS[n]);

            // gates: 4 class tiles, K=64 via chained MFMA pair, C = 0.
            // Issue order 2,1,0,3: cz-critical gates first.
            f32x4 acc[4];
            acc[2] = __builtin_amdgcn_mfma_f32_16x16x32_f16(a1, bfrag[2][1], zeroq, 0, 0, 0);
            acc[2] = __builtin_amdgcn_mfma_f32_16x16x32_f16(a0, bfrag[2][0], acc[2], 0, 0, 0);
            acc[1] = __builtin_amdgcn_mfma_f32_16x16x32_f16(a1, bfrag[1][1], zeroq, 0, 0, 0);
            acc[1] = __builtin_amdgcn_mfma_f32_16x16x32_f16(a0, bfrag[1][0], acc[1], 0, 0, 0);
            acc[0] = __builtin_amdgcn_mfma_f32_16x16x32_f16(a1, bfrag[0][1], zeroq, 0, 0, 0);
            acc[0] = __builtin_amdgcn_mfma_f32_16x16x32_f16(a0, bfrag[0][0], acc[0], 0, 0, 0);
            acc[3] = __builtin_amdgcn_mfma_f32_16x16x32_f16(a1, bfrag[3][1], zeroq, 0, 0, 0);
            acc[3] = __builtin_amdgcn_mfma_f32_16x16x32_f16(a0, bfrag[3][0], acc[3], 0, 0, 0);

            // rows 4q..4q+3 are all batch q -> elem 0, no select needed;
            // cz-critical v2, v1 assembled first
            float v2 = acc[2][0] + xb[2];
            float v1 = acc[1][0] + xb[1];
            float v0 = acc[0][0] + xb[0];
            float v3 = acc[3][0] + xb[3];

            // fused activations, cz = cs*K2 domain; lane owns (q, 16w+c)
            {
                float Bt  = ex2(v2);                    // e^{2g}  (cz-critical)
                float rf  = rcp_fast(1.0f + ex2(v1));   // sig(f)  (cz-critical)
                float A   = ex2(v0);                    // e^{-i}
                float Ao  = ex2(v3);                    // e^{-o}
                float R   = rcp_fast((1.0f + A) * (1.0f + Bt));
                float igk = fmaf(Bt, K2, -K2) * R;      // i*g * K2
                cz = fmaf(cz, rf, igk);
                float Ro  = rcp_fast(1.0f + Ao);        // off cz path
                float m2R = -2.0f * Ro;                 // off cz path
                float cc  = fminf(cz, CZMX);            // one-sided clamp
                float C   = ex2(cc);                    // e^{2c}
                float h   = fmaf(m2R, rcp_fast(1.0f + C), Ro);
                hbuf[rb ^ 1][q * HSTR + 16 * w + c] = (_Float16)h;
            }
            __syncthreads();
        }
    }

    // epilogue pending fc-dot: saved frag from tq=127 -> st = 508+w,
    // column 507+w (covers 507..510)
    {
        float s = out_dot(sa0, sa1, wfc0, wfc1);
        if (lane < 16 && (lane & 3) == 0)
            ols[(lane >> 2) * OSTRIDE + (507 + w)] = s + bfc;
    }

    // final output column: h_511 lives in hbuf[0]
    if (w == 3) {
        const _Float16* hp = hbuf[0] + (c >> 2) * HSTR + 8 * q;
        half8v a0 = *(const half8v*)(hp);
        half8v a1 = *(const half8v*)(hp + 32);
        float s = out_dot(a0, a1, wfc0, wfc1);
        if (lane < 16 && (lane & 3) == 0)
            ols[(lane >> 2) * OSTRIDE + (T_STEPS - 1)] = s + bfc;
    }
    __syncthreads();

    // bulk store: LDS out -> global, coalesced
    for (int i = tid; i < NB * T_STEPS; i += 256) {
        int b = i >> 9;
        int t = i & (T_STEPS - 1);
        out[(size_t)(b0 + b) * T_STEPS + t] = ols[b * OSTRIDE + t];
    }
}

extern "C" void kernel_launch(void* const* d_in, const int* in_sizes, int n_in,
                              void* d_out, int out_size, void* d_ws, size_t ws_size,
                              hipStream_t stream) {
    const float* x    = (const float*)d_in[0];
    const float* w_ih = (const float*)d_in[1];
    const float* w_hh = (const float*)d_in[2];
    const float* b_ih = (const float*)d_in[3];
    const float* b_hh = (const float*)d_in[4];
    const float* w_fc = (const float*)d_in[5];
    const float* b_fc = (const float*)d_in[6];
    float* out = (float*)d_out;
    hipLaunchKernelGGL(lstm_kernel, dim3(2048 / NB), dim3(256), 0, stream,
                       x, w_ih, w_hh, b_ih, b_hh, w_fc, b_fc, out);
}

// Round 10
// 246.005 us; speedup vs baseline: 1.0541x; 1.0173x over previous
//
#include <hip/hip_runtime.h>

#define T_STEPS 512
#define HSTR 80        // _Float16 per h batch-row (160 B)
#define XSTRIDE 520    // _Float16 per x-row
#define OSTRIDE 513    // floats per out-row
#define NB 4           // batches per block; 512 blocks = 2 blocks/CU

typedef _Float16 half8v __attribute__((ext_vector_type(8)));
typedef _Float16 half4v __attribute__((ext_vector_type(4)));
typedef float f32x4 __attribute__((ext_vector_type(4)));

#define K1 1.442695041f    // log2(e)
#define K2 2.885390082f    // 2*log2(e)
#define CZCL 43.28085123f  // 15 * K2 (clamp in cz = cs*K2 domain)

__device__ __forceinline__ float ex2(float x) {
#if __has_builtin(__builtin_amdgcn_exp2f)
    return __builtin_amdgcn_exp2f(x);
#else
    return exp2f(x);
#endif
}
__device__ __forceinline__ float rcp_fast(float x) {
#if __has_builtin(__builtin_amdgcn_rcpf)
    return __builtin_amdgcn_rcpf(x);
#else
    return 1.0f / x;
#endif
}

// partial fc-dot over this lane's A-frag slice (f16), reduced over the 4 k-quads
__device__ __forceinline__ float out_dot(half8v a0, half8v a1,
                                         const float* wfc0, const float* wfc1) {
    float s = 0.f;
#pragma unroll
    for (int j = 0; j < 8; ++j) s = fmaf((float)a0[j], wfc0[j], s);
#pragma unroll
    for (int j = 0; j < 8; ++j) s = fmaf((float)a1[j], wfc1[j], s);
    s += __shfl_xor(s, 16);
    s += __shfl_xor(s, 32);
    return s;   // full 64-dot for batch (c>>2), on all lanes
}

// R20 = R15 champion, LOCKED (verbatim revert). Session evidence:
//  - wave-topology mutations (dual-group R12, stagger R13, 2-wave R14,
//    barrier-free 1-wave R16) all regress 30-70%: the 4-wave/1-barrier
//    period (~990 cyc/step) is the measured structural floor.
//  - MFMA un-chain (R17/R18) costs +12us: chained C-forwarding wins.
//  - act micro-edits (R19 trio) are noise-negative: scheduling butterfly
//    outweighs dependency-graph gains at this scale.
// Structure: NB=4, 4 waves, 2 blocks/CU, A rows m -> h[m>>2] (dup-4, batch
// = q, unit 16w+c, one act chain/lane), chained K=64 MFMA pairs, cz =
// cs*K2 domain, fc-dot in the dt==0 ds_read latency shadow, 1 barrier/step.
__global__ __launch_bounds__(256, 2) void lstm_kernel(
    const float* __restrict__ x, const float* __restrict__ w_ih,
    const float* __restrict__ w_hh, const float* __restrict__ b_ih,
    const float* __restrict__ b_hh, const float* __restrict__ w_fc,
    const float* __restrict__ b_fc, float* __restrict__ out)
{
    __shared__ __align__(16) _Float16 hbuf[2][NB * HSTR];   // 1.3 KB
    __shared__ __align__(16) _Float16 xls[NB * XSTRIDE];    // 4.2 KB
    __shared__ __align__(16) float ols[NB * OSTRIDE];       // 8.2 KB

    const int tid  = threadIdx.x;
    const int w    = tid >> 6;        // wave 0..3
    const int lane = tid & 63;
    const int q    = lane >> 4;       // quad (A k-group / D row-group)
    const int c    = lane & 15;       // unit-in-tile / A-row
    const int b0   = blockIdx.x * NB;

    // ---- stage x: global -> LDS (f16), coalesced float4 reads ----
    for (int i = tid; i < NB * 128; i += 256) {      // 4 rows x 128 float4
        int b  = i >> 7;
        int t4 = i & 127;
        float4 v = *(const float4*)(x + (size_t)(b0 + b) * T_STEPS + t4 * 4);
        half4v hv;
        hv[0] = (_Float16)v.x; hv[1] = (_Float16)v.y;
        hv[2] = (_Float16)v.z; hv[3] = (_Float16)v.w;
        *(half4v*)(&xls[b * XSTRIDE + t4 * 4]) = hv;
    }
    // zero both h buffers (h_{-1} = 0)
    for (int i = tid; i < 2 * NB * HSTR / 2; i += 256) ((int*)hbuf)[i] = 0;

    // ---- B fragments (prescaled weights): tile n = gate class ----
    // lane (q,c) holds B[k=32kk+8q+jj][col c] = sK[n]*w_hh[g][k], g = 64n+16w+c
    const float sK[4] = { -K1, -K1, K2, -K1 };   // i,f sig; g tanh; o sig
    half8v bfrag[4][2];
    float biasS[4], wihS[4];
#pragma unroll
    for (int n = 0; n < 4; ++n) {
        int g = 64 * n + 16 * w + c;
        biasS[n] = (b_ih[g] + b_hh[g]) * sK[n];
        wihS[n]  = w_ih[g] * sK[n];
#pragma unroll
        for (int kk = 0; kk < 2; ++kk) {
            const float* wp = w_hh + g * 64 + 32 * kk + 8 * q;
            float4 lo  = *(const float4*)(wp);
            float4 hi4 = *(const float4*)(wp + 4);
            half8v f;
            f[0] = (_Float16)(lo.x  * sK[n]); f[1] = (_Float16)(lo.y  * sK[n]);
            f[2] = (_Float16)(lo.z  * sK[n]); f[3] = (_Float16)(lo.w  * sK[n]);
            f[4] = (_Float16)(hi4.x * sK[n]); f[5] = (_Float16)(hi4.y * sK[n]);
            f[6] = (_Float16)(hi4.z * sK[n]); f[7] = (_Float16)(hi4.w * sK[n]);
            bfrag[n][kk] = f;
        }
    }

    // fc weights aligned to this lane's A-frag k-slice
    float wfc0[8], wfc1[8];
#pragma unroll
    for (int j = 0; j < 8; ++j) { wfc0[j] = w_fc[8 * q + j]; wfc1[j] = w_fc[32 + 8 * q + j]; }
    const float bfc = b_fc[0];

    float cz = 0.f;               // cell state * K2 (batch q, unit 16w+c)
    const f32x4 zeroq = {0.f, 0.f, 0.f, 0.f};

    __syncthreads();

    half8v sa0 = {}, sa1 = {};  // saved A-frags for rotated fc-dot

    for (int tq = 0; tq < 128; ++tq) {
        // x for this lane's OWN batch (q), 4 steps (broadcast read)
        half4v xh = *(const half4v*)(&xls[q * XSTRIDE + tq * 4]);

#pragma unroll
        for (int dt = 0; dt < 4; ++dt) {
            const int t  = tq * 4 + dt;
            const int rb = t & 1;

            // A-frags: A[m][k] = h[m>>2][k]; lane row m=c -> LDS row c>>2
            const _Float16* hp = hbuf[rb] + (c >> 2) * HSTR + 8 * q;
            half8v a0 = *(const half8v*)(hp);        // k = 8q+j
            half8v a1 = *(const half8v*)(hp + 32);   // k = 32+8q+j

            if (dt == 0) {
                // pending fc-dot from previous tq, issued in the ds_read
                // latency shadow (independent of a0/a1). Saved frag was the
                // A of step stp = 4(tq-1)+w = h(stp-1) -> column stp-1.
                int stp = 4 * tq - 4 + w;
                if (tq > 0 && stp > 0) {
                    float s = out_dot(sa0, sa1, wfc0, wfc1);
                    if (lane < 16 && (lane & 3) == 0)
                        ols[(lane >> 2) * OSTRIDE + (stp - 1)] = s + bfc;
                }
            }

            if (dt == w) { sa0 = a0; sa1 = a1; }     // rotate fc-dot ownership

            // scalar x*wih+bias for the owned batch (off critical path)
            const float xv = (float)xh[dt];
            float xb[4];
#pragma unroll
            for (int n = 0; n < 4; ++n) xb[n] = fmaf(xv, wihS[n], biasS[n]);

            // gates: 4 class tiles, K=64 via chained MFMA pair, C = 0
            f32x4 acc[4];
#pragma unroll
            for (int n = 0; n < 4; ++n) {
                acc[n] = __builtin_amdgcn_mfma_f32_16x16x32_f16(a1, bfrag[n][1], zeroq, 0, 0, 0);
                acc[n] = __builtin_amdgcn_mfma_f32_16x16x32_f16(a0, bfrag[n][0], acc[n], 0, 0, 0);
            }

            // rows 4q..4q+3 are all batch q -> elem 0, no select needed
            float v0 = acc[0][0] + xb[0];
            float v1 = acc[1][0] + xb[1];
            float v2 = acc[2][0] + xb[2];
            float v3 = acc[3][0] + xb[3];

            // fused activations, cz = cs*K2 domain; lane owns (q, 16w+c)
            {
                float A   = ex2(v0);                    // e^{-i}
                float Bt  = ex2(v2);                    // e^{2g}
                float R   = rcp_fast((1.0f + A) * (1.0f + Bt));
                float pg  = fmaf(Bt, K2, -K2);          // (Bt-1)*K2
                float igk = pg * R;                     // i*g * K2
                float rf  = rcp_fast(1.0f + ex2(v1));   // sig(f)
                cz = fmaf(cz, rf, igk);
                float cc = fminf(fmaxf(cz, -CZCL), CZCL);
                float Ao = ex2(v3);                     // e^{-o}
                float C  = ex2(cc);                     // e^{2c}
                float h  = (C - 1.0f) * rcp_fast((1.0f + Ao) * (1.0f + C));
                hbuf[rb ^ 1][q * HSTR + 16 * w + c] = (_Float16)h;
            }
            __syncthreads();
        }
    }

    // epilogue pending fc-dot: saved frag from tq=127 -> st = 508+w,
    // column 507+w (covers 507..510)
    {
        float s = out_dot(sa0, sa1, wfc0, wfc1);
        if (lane < 16 && (lane & 3) == 0)
            ols[(lane >> 2) * OSTRIDE + (507 + w)] = s + bfc;
    }

    // final output column: h_511 lives in hbuf[0]
    if (w == 3) {
        const _Float16* hp = hbuf[0] + (c >> 2) * HSTR + 8 * q;
        half8v a0 = *(const half8v*)(hp);
        half8v a1 = *(const half8v*)(hp + 32);
        float s = out_dot(a0, a1, wfc0, wfc1);
        if (lane < 16 && (lane & 3) == 0)
            ols[(lane >> 2) * OSTRIDE + (T_STEPS - 1)] = s + bfc;
    }
    __syncthreads();

    // bulk store: LDS out -> global, coalesced
    for (int i = tid; i < NB * T_STEPS; i += 256) {
        int b = i >> 9;
        int t = i & (T_STEPS - 1);
        out[(size_t)(b0 + b) * T_STEPS + t] = ols[b * OSTRIDE + t];
    }
}

extern "C" void kernel_launch(void* const* d_in, const int* in_sizes, int n_in,
                              void* d_out, int out_size, void* d_ws, size_t ws_size,
                              hipStream_t stream) {
    const float* x    = (const float*)d_in[0];
    const float* w_ih = (const float*)d_in[1];
    const float* w_hh = (const float*)d_in[2];
    const float* b_ih = (const float*)d_in[3];
    const float* b_hh = (const float*)d_in[4];
    const float* w_fc = (const float*)d_in[5];
    const float* b_fc = (const float*)d_in[6];
    float* out = (float*)d_out;
    hipLaunchKernelGGL(lstm_kernel, dim3(2048 / NB), dim3(256), 0, stream,
                       x, w_ih, w_hh, b_ih, b_hh, w_fc, b_fc, out);
}